// Round 1
// baseline (1514.529 us; speedup 1.0000x reference)
//
#include <hip/hip_runtime.h>
#include <math.h>

#define NN 8192
#define DD 256
#define EPSV 1e-6f
#define BM 64
#define BN 64
#define CSPLIT 4
#define COLS_PER_BLOCK (NN / CSPLIT)  // 2048
#define NJT (COLS_PER_BLOCK / BN)     // 32
#define LDSP 68                       // padded LDS stride (floats), 16B-aligned, conflict-free

// ws layout (floats): Oacc[NN*DD] | lacc[NN] | qn[NN] | tv[NN]

__global__ void zero_kernel(float* __restrict__ p) {
    int i = blockIdx.x * 256 + threadIdx.x;
    ((float4*)p)[i] = make_float4(0.f, 0.f, 0.f, 0.f);
}

__global__ void qn_kernel(const float* __restrict__ q, const float* __restrict__ cp,
                          float* __restrict__ qn, float* __restrict__ tv) {
    int row = blockIdx.x * 4 + (threadIdx.x >> 6);
    int lane = threadIdx.x & 63;
    const float4* q4 = (const float4*)(q + (size_t)row * DD);
    float4 v = q4[lane];
    float s = v.x * v.x + v.y * v.y + v.z * v.z + v.w * v.w;
    #pragma unroll
    for (int off = 32; off; off >>= 1) s += __shfl_xor(s, off, 64);
    if (lane == 0) {
        float cc = fmaxf(cp[0], EPSV);
        qn[row] = s;
        tv[row] = fmaxf(1.0f - cc * s, EPSV);
    }
}

__global__ __launch_bounds__(256, 2) void flash_kernel(
    const float* __restrict__ q, const float* __restrict__ cp,
    const float* __restrict__ qn, const float* __restrict__ tv,
    float* __restrict__ Oacc, float* __restrict__ lacc) {
    __shared__ float Qs[32][LDSP];  // [k][row]  (transposed)
    __shared__ float Ks[32][LDSP];  // [k][col]  (transposed)
    __shared__ float Ps[BM][LDSP];  // [row][col]
    __shared__ float Kv[BN][LDSP];  // [j][c]

    const int tid = threadIdx.x;
    const int tx = tid & 15;
    const int ty = tid >> 4;
    const int R0 = blockIdx.y * BM;
    const int C0 = blockIdx.x * COLS_PER_BLOCK;

    const float cc = fmaxf(cp[0], EPSV);
    const float rsc = rsqrtf(cc);

    float qnr[4], tr[4];
    #pragma unroll
    for (int a = 0; a < 4; ++a) {
        int r = R0 + ty * 4 + a;
        qnr[a] = qn[r];
        tr[a] = tv[r];
    }

    float O[4][16];
    #pragma unroll
    for (int a = 0; a < 4; ++a)
        #pragma unroll
        for (int c = 0; c < 16; ++c) O[a][c] = 0.f;
    float lpart[4] = {0.f, 0.f, 0.f, 0.f};

    const int srow = tid >> 3;  // 0..31
    const int skq = tid & 7;    // 0..7

    for (int jt = 0; jt < NJT; ++jt) {
        const int C = C0 + jt * BN;

        // ---------- S = Q_tile . K_tile^T ----------
        float acc[4][4];
        #pragma unroll
        for (int a = 0; a < 4; ++a)
            #pragma unroll
            for (int b = 0; b < 4; ++b) acc[a][b] = 0.f;

        for (int kc = 0; kc < 8; ++kc) {
            const int k0 = kc * 32;
            __syncthreads();
            {
                float4 va = *(const float4*)(q + (size_t)(R0 + srow) * DD + k0 + skq * 4);
                float4 vb = *(const float4*)(q + (size_t)(R0 + srow + 32) * DD + k0 + skq * 4);
                Qs[skq * 4 + 0][srow] = va.x; Qs[skq * 4 + 1][srow] = va.y;
                Qs[skq * 4 + 2][srow] = va.z; Qs[skq * 4 + 3][srow] = va.w;
                Qs[skq * 4 + 0][srow + 32] = vb.x; Qs[skq * 4 + 1][srow + 32] = vb.y;
                Qs[skq * 4 + 2][srow + 32] = vb.z; Qs[skq * 4 + 3][srow + 32] = vb.w;
                float4 wa = *(const float4*)(q + (size_t)(C + srow) * DD + k0 + skq * 4);
                float4 wb = *(const float4*)(q + (size_t)(C + srow + 32) * DD + k0 + skq * 4);
                Ks[skq * 4 + 0][srow] = wa.x; Ks[skq * 4 + 1][srow] = wa.y;
                Ks[skq * 4 + 2][srow] = wa.z; Ks[skq * 4 + 3][srow] = wa.w;
                Ks[skq * 4 + 0][srow + 32] = wb.x; Ks[skq * 4 + 1][srow + 32] = wb.y;
                Ks[skq * 4 + 2][srow + 32] = wb.z; Ks[skq * 4 + 3][srow + 32] = wb.w;
            }
            __syncthreads();
            #pragma unroll 8
            for (int kk = 0; kk < 32; ++kk) {
                float4 qa = *(const float4*)&Qs[kk][ty * 4];
                float4 kb = *(const float4*)&Ks[kk][tx * 4];
                float qv[4] = {qa.x, qa.y, qa.z, qa.w};
                float kv[4] = {kb.x, kb.y, kb.z, kb.w};
                #pragma unroll
                for (int a = 0; a < 4; ++a)
                    #pragma unroll
                    for (int b = 0; b < 4; ++b) acc[a][b] = fmaf(qv[a], kv[b], acc[a][b]);
            }
        }

        // ---------- elementwise hyperbolic distance -> P ----------
        #pragma unroll
        for (int a = 0; a < 4; ++a) {
            float pv[4];
            #pragma unroll
            for (int b = 0; b < 4; ++b) {
                int colj = C + tx * 4 + b;
                float qnj = qn[colj];
                float tj = tv[colj];
                float diff = fmaxf(qnr[a] + qnj - 2.0f * acc[a][b], 0.0f);
                float arg = fmaxf(1.0f + 2.0f * cc * diff / (tr[a] * tj), 1.0f + EPSV) + EPSV;
                float dist = acoshf(arg) * rsc;
                pv[b] = expf(-dist);
            }
            float4 pq = make_float4(pv[0], pv[1], pv[2], pv[3]);
            *(float4*)&Ps[ty * 4 + a][tx * 4] = pq;
        }
        __syncthreads();

        // ---------- O += P . K_tile ----------
        #pragma unroll
        for (int chunk = 0; chunk < 4; ++chunk) {
            {
                int j = tid >> 2;   // 0..63
                int cq = tid & 3;   // 0..3
                #pragma unroll
                for (int i = 0; i < 4; ++i) {
                    float4 v = *(const float4*)(q + (size_t)(C + j) * DD + chunk * 64 + cq * 16 + i * 4);
                    *(float4*)&Kv[j][cq * 16 + i * 4] = v;
                }
            }
            __syncthreads();
            #pragma unroll 2
            for (int j4 = 0; j4 < 16; ++j4) {
                float4 p0 = *(const float4*)&Ps[ty * 4 + 0][j4 * 4];
                float4 p1 = *(const float4*)&Ps[ty * 4 + 1][j4 * 4];
                float4 p2 = *(const float4*)&Ps[ty * 4 + 2][j4 * 4];
                float4 p3 = *(const float4*)&Ps[ty * 4 + 3][j4 * 4];
                float pm[4][4] = {{p0.x, p0.y, p0.z, p0.w},
                                  {p1.x, p1.y, p1.z, p1.w},
                                  {p2.x, p2.y, p2.z, p2.w},
                                  {p3.x, p3.y, p3.z, p3.w}};
                float4 k0v = *(const float4*)&Kv[j4 * 4 + 0][tx * 4];
                float4 k1v = *(const float4*)&Kv[j4 * 4 + 1][tx * 4];
                float4 k2v = *(const float4*)&Kv[j4 * 4 + 2][tx * 4];
                float4 k3v = *(const float4*)&Kv[j4 * 4 + 3][tx * 4];
                float km[4][4] = {{k0v.x, k0v.y, k0v.z, k0v.w},
                                  {k1v.x, k1v.y, k1v.z, k1v.w},
                                  {k2v.x, k2v.y, k2v.z, k2v.w},
                                  {k3v.x, k3v.y, k3v.z, k3v.w}};
                #pragma unroll
                for (int jj = 0; jj < 4; ++jj)
                    #pragma unroll
                    for (int a = 0; a < 4; ++a)
                        #pragma unroll
                        for (int b = 0; b < 4; ++b)
                            O[a][chunk * 4 + b] = fmaf(pm[a][jj], km[jj][b], O[a][chunk * 4 + b]);
                if (chunk == 0 && tx == 0) {
                    #pragma unroll
                    for (int a = 0; a < 4; ++a)
                        lpart[a] += pm[a][0] + pm[a][1] + pm[a][2] + pm[a][3];
                }
            }
            __syncthreads();
        }
    }

    // ---------- epilogue: accumulate partials ----------
    #pragma unroll
    for (int a = 0; a < 4; ++a) {
        int r = R0 + ty * 4 + a;
        #pragma unroll
        for (int chunk = 0; chunk < 4; ++chunk)
            #pragma unroll
            for (int b = 0; b < 4; ++b)
                atomicAdd(&Oacc[(size_t)r * DD + chunk * 64 + tx * 4 + b], O[a][chunk * 4 + b]);
        if (tx == 0) atomicAdd(&lacc[r], lpart[a]);
    }
}

__global__ void norm_kernel(const float* __restrict__ Oacc, const float* __restrict__ lacc,
                            float* __restrict__ out) {
    int i = blockIdx.x * 256 + threadIdx.x;  // index over float4s
    float4 v = ((const float4*)Oacc)[i];
    float l = lacc[i >> 6];  // DD/4 = 64 float4 per row
    float inv = 1.0f / l;
    float4 r = make_float4(v.x * inv, v.y * inv, v.z * inv, v.w * inv);
    ((float4*)out)[i] = r;
}

extern "C" void kernel_launch(void* const* d_in, const int* in_sizes, int n_in,
                              void* d_out, int out_size, void* d_ws, size_t ws_size,
                              hipStream_t stream) {
    (void)in_sizes; (void)n_in; (void)out_size; (void)ws_size;
    const float* q = (const float*)d_in[0];
    const float* cp = (const float*)d_in[1];
    float* out = (float*)d_out;
    float* ws = (float*)d_ws;
    float* Oacc = ws;
    float* lacc = ws + (size_t)NN * DD;
    float* qn = lacc + NN;
    float* tv = qn + NN;

    // zero Oacc + lacc: (NN*DD + NN) floats = 2105344 -> 526336 float4 -> 2056 blocks
    zero_kernel<<<(NN * DD + NN) / 4 / 256, 256, 0, stream>>>(ws);
    qn_kernel<<<NN / 4, 256, 0, stream>>>(q, cp, qn, tv);
    flash_kernel<<<dim3(CSPLIT, NN / BM), 256, 0, stream>>>(q, cp, qn, tv, Oacc, lacc);
    norm_kernel<<<(NN * DD / 4) / 256, 256, 0, stream>>>(Oacc, lacc, out);
}

// Round 2
// 209.728 us; speedup vs baseline: 7.2214x; 7.2214x over previous
//
#include <hip/hip_runtime.h>
#include <math.h>

#define NN 8192
#define DD 256
#define EPSV 1e-6f
#define BM 64
#define BN 64
#define CSPLIT 4
#define COLS_PER_BLOCK (NN / CSPLIT)  // 2048
#define NJT (COLS_PER_BLOCK / BN)     // 32
#define PSTR 72                       // P LDS row stride (bf16 elems), 16B aligned, conflict-free
#define SMEM_BYTES (32768 + 32768 + BM * PSTR * 2)  // K + Kt + P = 74752

typedef __bf16 bf16x8 __attribute__((ext_vector_type(8)));
typedef float f32x16 __attribute__((ext_vector_type(16)));
typedef unsigned short ushort;
typedef unsigned int uint;

// ws layout (floats): Oacc[NN*DD] | lacc[NN] | qn[NN] | itv[NN] | qbf[NN*DD/2] | qbfT[NN*DD/2]

__device__ inline ushort f2bf(float x) {
    uint u = __float_as_uint(x);
    u += 0x7fffu + ((u >> 16) & 1u);
    return (ushort)(u >> 16);
}

__device__ inline void gload_lds16(const void* g, void* l) {
    __builtin_amdgcn_global_load_lds((const __attribute__((address_space(1))) uint*)g,
                                     (__attribute__((address_space(3))) uint*)l, 16, 0, 0);
}

__global__ void zero_kernel(float* __restrict__ p) {
    int i = blockIdx.x * 256 + threadIdx.x;
    ((float4*)p)[i] = make_float4(0.f, 0.f, 0.f, 0.f);
}

// q (fp32) -> qbf (bf16, row-major, 16B-chunk swizzled: chunk c stored at c ^ (row&7))
__global__ void cvt_kernel(const float* __restrict__ q, ushort* __restrict__ qbf) {
    int g = blockIdx.x * 256 + threadIdx.x;
    int r = g >> 5, c = g & 31;
    const float4* src = (const float4*)(q + (size_t)r * DD + c * 8);
    float4 v0 = src[0], v1 = src[1];
    ushort o[8] = {f2bf(v0.x), f2bf(v0.y), f2bf(v0.z), f2bf(v0.w),
                   f2bf(v1.x), f2bf(v1.y), f2bf(v1.z), f2bf(v1.w)};
    *(uint4*)(qbf + (size_t)r * DD + ((c ^ (r & 7)) * 8)) = *(uint4*)o;
}

// q (fp32) -> qbfT (bf16, [DD][NN], per-row 16B-chunk g stored at g ^ (feat&7))
__global__ void tr_kernel(const float* __restrict__ q, ushort* __restrict__ qbfT) {
    __shared__ ushort T[64 * PSTR];
    int p0 = blockIdx.x * 64, f0 = blockIdx.y * 64;
    int t = threadIdx.x;
    int pr = t >> 2, fs = (t & 3) * 16;
    const float4* src = (const float4*)(q + (size_t)(p0 + pr) * DD + f0 + fs);
    #pragma unroll
    for (int i = 0; i < 4; ++i) {
        float4 v = src[i];
        ushort o[4] = {f2bf(v.x), f2bf(v.y), f2bf(v.z), f2bf(v.w)};
        *(ushort4*)&T[pr * PSTR + fs + i * 4] = *(ushort4*)o;
    }
    __syncthreads();
    int fr = t >> 2;
    int f = f0 + fr;
    #pragma unroll
    for (int half = 0; half < 2; ++half) {
        int cgpos = (t & 3) * 2 + half;      // stored chunk position 0..7
        int cg = cgpos ^ (f & 7);            // logical point-chunk
        ushort tmp[8];
        #pragma unroll
        for (int j = 0; j < 8; ++j) tmp[j] = T[(cg * 8 + j) * PSTR + fr];
        *(uint4*)(qbfT + (size_t)f * NN + p0 + cgpos * 8) = *(uint4*)tmp;
    }
}

// qn from bf16-rounded q (keeps diagonal diff exactly 0), itv = 1/clamped t
__global__ void qn_kernel(const float* __restrict__ q, const float* __restrict__ cp,
                          float* __restrict__ qn, float* __restrict__ itv) {
    int row = blockIdx.x * 4 + (threadIdx.x >> 6);
    int lane = threadIdx.x & 63;
    float4 v = ((const float4*)(q + (size_t)row * DD))[lane];
    float a = __uint_as_float((uint)f2bf(v.x) << 16);
    float b = __uint_as_float((uint)f2bf(v.y) << 16);
    float c2 = __uint_as_float((uint)f2bf(v.z) << 16);
    float d = __uint_as_float((uint)f2bf(v.w) << 16);
    float s = a * a + b * b + c2 * c2 + d * d;
    #pragma unroll
    for (int off = 32; off; off >>= 1) s += __shfl_xor(s, off, 64);
    if (lane == 0) {
        float cc = fmaxf(cp[0], EPSV);
        qn[row] = s;
        float tt = fmaxf(1.0f - cc * s, EPSV);
        itv[row] = 1.0f / tt;
    }
}

__global__ __launch_bounds__(256, 2) void flash_kernel(
    const ushort* __restrict__ qbf, const ushort* __restrict__ qbfT,
    const float* __restrict__ cp, const float* __restrict__ qn,
    const float* __restrict__ itv, float* __restrict__ Oacc, float* __restrict__ lacc) {
    extern __shared__ char smem[];
    ushort* Klds = (ushort*)smem;              // [64][256] swizzled, 32 KB
    ushort* Ktlds = (ushort*)(smem + 32768);   // [256][64] swizzled, 32 KB
    ushort* Plds = (ushort*)(smem + 65536);    // [64][PSTR]

    const int tid = threadIdx.x;
    const int lane = tid & 63;
    const int w = tid >> 6;
    const int l31 = lane & 31;
    const int lhi = lane >> 5;  // 0/1
    const int qr = w >> 1;      // row quad (S rows 32*qr)
    const int qc = w & 1;       // col quad (S cols 32*qc; O feats 128*qc)
    const int R0 = blockIdx.y * BM;
    const int C0 = blockIdx.x * COLS_PER_BLOCK;

    const float cc = fmaxf(cp[0], EPSV);
    const float rsc = rsqrtf(cc);
    const float k2c = 2.0f * cc;

    // ---- persistent Q A-fragments (32 rows x 256 K) ----
    const int rowA = R0 + qr * 32 + l31;
    const ushort* qrow = qbf + (size_t)rowA * DD;
    bf16x8 qa[16];
    #pragma unroll
    for (int kk = 0; kk < 16; ++kk) {
        int c = kk * 2 + lhi;
        qa[kk] = *(const bf16x8*)(qrow + ((c ^ (rowA & 7)) * 8));
    }

    // per-row qn / itv for the 16 C-rows this lane owns
    float qnr16[16], itr16[16];
    #pragma unroll
    for (int r = 0; r < 16; ++r) {
        int row = R0 + qr * 32 + (r & 3) + 8 * (r >> 2) + 4 * lhi;
        qnr16[r] = qn[row];
        itr16[r] = itv[row];
    }

    f32x16 o[4];
    #pragma unroll
    for (int ct = 0; ct < 4; ++ct)
        #pragma unroll
        for (int i = 0; i < 16; ++i) o[ct][i] = 0.f;
    float rsum = 0.f;

    // ---- stage K(0): rows C0..C0+63 of qbf, contiguous 32KB, 8 chunks/wave ----
    {
        const char* gbase = (const char*)(qbf + (size_t)C0 * DD);
        #pragma unroll
        for (int i = 0; i < 8; ++i) {
            int chunk = w * 8 + i;
            gload_lds16(gbase + chunk * 1024 + lane * 16, (char*)Klds + chunk * 1024);
        }
    }

    for (int jt = 0; jt < NJT; ++jt) {
        const int C = C0 + jt * BN;
        __syncthreads();  // A: K(jt) arrived; prev PV reads of Kt/P done

        // ---- stage Kt(jt): gather from qbfT, awaited at sync B ----
        {
            int fr = lane >> 3, cg = lane & 7;
            #pragma unroll
            for (int i = 0; i < 8; ++i) {
                int f0 = w * 64 + i * 8;
                gload_lds16((const char*)(qbfT + (size_t)(f0 + fr) * NN + C) + cg * 16,
                            (char*)Ktlds + f0 * 128 + lane * 16);
            }
        }

        // ---- S = Q . K^T (this wave: rows 32*qr, cols 32*qc) ----
        f32x16 s;
        #pragma unroll
        for (int i = 0; i < 16; ++i) s[i] = 0.f;
        const int jrow = qc * 32 + l31;
        const ushort* krow = Klds + jrow * DD;
        #pragma unroll
        for (int kk = 0; kk < 16; ++kk) {
            int c = kk * 2 + lhi;
            bf16x8 b = *(const bf16x8*)(krow + ((c ^ (jrow & 7)) * 8));
            s = __builtin_amdgcn_mfma_f32_32x32x16_bf16(qa[kk], b, s, 0, 0, 0);
        }

        // ---- elementwise hyperbolic -> P (bf16, LDS) ----
        {
            int J = C + jrow;
            float qnj = qn[J];
            float itj = itv[J];
            #pragma unroll
            for (int r = 0; r < 16; ++r) {
                int mloc = qr * 32 + (r & 3) + 8 * (r >> 2) + 4 * lhi;
                float diff = fmaxf(qnr16[r] + qnj - 2.0f * s[r], 0.0f);
                float u = k2c * diff * itr16[r] * itj;
                float arg = fmaxf(1.0f + u, 1.0f + EPSV) + EPSV;
                float y = arg + sqrtf((arg - 1.0f) * (arg + 1.0f));
                float p = __builtin_amdgcn_exp2f(-rsc * __builtin_amdgcn_logf(y));
                Plds[mloc * PSTR + jrow] = f2bf(p);
            }
        }
        __syncthreads();  // B: P + Kt ready; all S reads of K done

        // ---- overlap: stage K(jt+1) during PV ----
        if (jt + 1 < NJT) {
            const char* gbase = (const char*)(qbf + (size_t)(C + BN) * DD);
            #pragma unroll
            for (int i = 0; i < 8; ++i) {
                int chunk = w * 8 + i;
                gload_lds16(gbase + chunk * 1024 + lane * 16, (char*)Klds + chunk * 1024);
            }
        }

        // ---- softmax denom partials from P (row tid>>2, cols (tid&3)*16..+15) ----
        {
            const ushort* prow = Plds + (tid >> 2) * PSTR + (tid & 3) * 16;
            uint4 a = *(const uint4*)prow;
            uint4 b = *(const uint4*)(prow + 8);
            uint ua[8] = {a.x, a.y, a.z, a.w, b.x, b.y, b.z, b.w};
            float ssum = 0.f;
            #pragma unroll
            for (int i = 0; i < 8; ++i) {
                ssum += __uint_as_float(ua[i] << 16);
                ssum += __uint_as_float(ua[i] & 0xffff0000u);
            }
            rsum += ssum;
        }

        // ---- O += P . V  (this wave: rows 32*qr, feats qc*128..+127) ----
        #pragma unroll
        for (int kt = 0; kt < 4; ++kt) {
            bf16x8 pa = *(const bf16x8*)&Plds[(qr * 32 + l31) * PSTR + kt * 16 + 8 * lhi];
            #pragma unroll
            for (int ct = 0; ct < 4; ++ct) {
                int drow = qc * 128 + ct * 32 + l31;
                int cch = kt * 2 + lhi;
                bf16x8 vb = *(const bf16x8*)(Ktlds + drow * 64 + ((cch ^ (drow & 7)) * 8));
                o[ct] = __builtin_amdgcn_mfma_f32_32x32x16_bf16(pa, vb, o[ct], 0, 0, 0);
            }
        }
    }

    // ---- epilogue ----
    #pragma unroll
    for (int ct = 0; ct < 4; ++ct) {
        #pragma unroll
        for (int r = 0; r < 16; ++r) {
            int row = R0 + qr * 32 + (r & 3) + 8 * (r >> 2) + 4 * lhi;
            int d = qc * 128 + ct * 32 + l31;
            atomicAdd(&Oacc[(size_t)row * DD + d], o[ct][r]);
        }
    }
    float tot = rsum;
    tot += __shfl_xor(tot, 1, 64);
    tot += __shfl_xor(tot, 2, 64);
    if ((tid & 3) == 0) atomicAdd(&lacc[R0 + (tid >> 2)], tot);
}

__global__ void norm_kernel(const float* __restrict__ Oacc, const float* __restrict__ lacc,
                            float* __restrict__ out) {
    int i = blockIdx.x * 256 + threadIdx.x;
    float4 v = ((const float4*)Oacc)[i];
    float inv = 1.0f / lacc[i >> 6];
    ((float4*)out)[i] = make_float4(v.x * inv, v.y * inv, v.z * inv, v.w * inv);
}

extern "C" void kernel_launch(void* const* d_in, const int* in_sizes, int n_in,
                              void* d_out, int out_size, void* d_ws, size_t ws_size,
                              hipStream_t stream) {
    (void)in_sizes; (void)n_in; (void)out_size; (void)ws_size;
    const float* q = (const float*)d_in[0];
    const float* cp = (const float*)d_in[1];
    float* out = (float*)d_out;
    float* ws = (float*)d_ws;
    float* Oacc = ws;
    float* lacc = ws + (size_t)NN * DD;
    float* qn = lacc + NN;
    float* itv = qn + NN;
    ushort* qbf = (ushort*)(itv + NN);
    ushort* qbfT = qbf + (size_t)NN * DD;

    static int smem_set = 0;
    if (!smem_set) {
        hipFuncSetAttribute((const void*)flash_kernel,
                            hipFuncAttributeMaxDynamicSharedMemorySize, SMEM_BYTES);
        smem_set = 1;
    }

    zero_kernel<<<(NN * DD + NN) / 4 / 256, 256, 0, stream>>>(ws);
    cvt_kernel<<<NN * DD / 8 / 256, 256, 0, stream>>>(q, qbf);
    tr_kernel<<<dim3(NN / 64, DD / 64), 256, 0, stream>>>(q, qbfT);
    qn_kernel<<<NN / 4, 256, 0, stream>>>(q, cp, qn, itv);
    flash_kernel<<<dim3(CSPLIT, NN / BM), 256, SMEM_BYTES, stream>>>(qbf, qbfT, cp, qn, itv, Oacc, lacc);
    norm_kernel<<<(NN * DD / 4) / 256, 256, 0, stream>>>(Oacc, lacc, out);
}